// Round 1
// baseline (486.658 us; speedup 1.0000x reference)
//
#include <hip/hip_runtime.h>
#include <math.h>

#define N_      64
#define M_      2080          // N*(N+1)/2
#define SORTN   4096
#define B_      32
#define TOPK_   5
#define NEIGH_  16
#define NEG_    16
#define TOTAL_  85            // TOPK*(NEIGHBOR+1)
#define KOUT_   101           // NEGATIVE + TOTAL
#define D_      512
#define NT_     256
#define CHUNK_  9             // ceil(2080/256)

// ---------------------------------------------------------------------------
// Kernel 1: per-batch proposal selection. One block per batch element.
// ---------------------------------------------------------------------------
__global__ __launch_bounds__(NT_) void select_kernel(
    const float* __restrict__ score_pred,   // [B,64,64]
    const float* __restrict__ offset_gt,    // [B,64,64,2]
    const float* __restrict__ tmap,         // [B,64,64]
    float* __restrict__ out_pse,            // [B*K,2]
    float* __restrict__ out_off,            // [B*K,2]
    float* __restrict__ out_score)          // [B*K]
{
    __shared__ float s_key[SORTN];
    __shared__ int   s_idx[SORTN];
    __shared__ unsigned char s_r[M_], s_c[M_];
    __shared__ unsigned char sm_s[M_], sm_e[M_];   // sorted moments (start,end)
    __shared__ unsigned char s_sup[M_], s_sel[M_];
    __shared__ int s_unsupidx[M_];
    __shared__ int s_selidx[TOTAL_];
    __shared__ int s_scan[NT_];
    __shared__ int s_nsel, s_nunsup;

    const int b   = blockIdx.x;
    const int tid = threadIdx.x;

    // ---- build m -> (r,c) triangle table (row-major upper-tri, c>=r) ----
    if (tid < N_) {
        int r  = tid;
        int rs = r * N_ - (r * (r - 1)) / 2;
        for (int k = 0; k < N_ - r; ++k) {
            s_r[rs + k] = (unsigned char)r;
            s_c[rs + k] = (unsigned char)(r + k);
        }
    }
    __syncthreads();

    // ---- load scores into padded sort arrays ----
    const float* sp = score_pred + (size_t)b * N_ * N_;
    for (int m = tid; m < SORTN; m += NT_) {
        if (m < M_) {
            int r = s_r[m], c = s_c[m];
            s_key[m] = sp[r * N_ + c];
        } else {
            s_key[m] = -INFINITY;
        }
        s_idx[m] = m;
    }
    __syncthreads();

    // ---- bitonic sort: descending score, ties -> ascending original idx
    //      (exactly replicates stable argsort(-scores)) ----
    for (int kk = 2; kk <= SORTN; kk <<= 1) {
        for (int j = kk >> 1; j > 0; j >>= 1) {
            for (int i = tid; i < SORTN; i += NT_) {
                int ixj = i ^ j;
                if (ixj > i) {
                    float ka = s_key[i], kb = s_key[ixj];
                    int   ia = s_idx[i], ib = s_idx[ixj];
                    bool aFirst = (ka > kb) || (ka == kb && ia < ib);
                    bool up     = ((i & kk) == 0);
                    if (up != aFirst) {
                        s_key[i] = kb; s_key[ixj] = ka;
                        s_idx[i] = ib; s_idx[ixj] = ia;
                    }
                }
            }
            __syncthreads();
        }
    }

    // ---- sorted moments + init sup/sel ----
    for (int jj = tid; jj < M_; jj += NT_) {
        int o = s_idx[jj];
        sm_s[jj] = s_r[o];
        sm_e[jj] = (unsigned char)(s_c[o] + 1);
        s_sup[jj] = 0;
        s_sel[jj] = 0;
    }
    __syncthreads();

    // ---- NMS while-loop (block-uniform control flow) ----
    const int j0 = tid * CHUNK_;
    const int j1 = (j0 + CHUNK_ < M_) ? j0 + CHUNK_ : M_;
    int i = 0, cnt = 0;
    while (cnt < TOPK_ && i < M_ - 1) {
        bool freei = (s_sup[i] == 0);      // uniform read (broadcast)
        if (freei) {
            const int si = sm_s[i], ei = sm_e[i];
            unsigned int mkbits = 0;
            int localcnt = 0;
            for (int t = 0; t < CHUNK_; ++t) {
                int jj = j0 + t;
                if (jj < M_ && jj > i) {
                    int s = sm_s[jj], e = sm_e[jj];
                    int inter = (e < ei ? e : ei) - (s > si ? s : si);
                    int uni   = (e > ei ? e : ei) - (s < si ? s : si);
                    if (inter > 0 && 2 * inter > uni) {   // iou > 0.5, exact
                        mkbits |= (1u << t);
                        ++localcnt;
                    }
                }
            }
            // exclusive block scan of localcnt
            s_scan[tid] = localcnt;
            __syncthreads();
            for (int off = 1; off < NT_; off <<= 1) {
                int t = (tid >= off) ? s_scan[tid - off] : 0;
                __syncthreads();
                s_scan[tid] += t;
                __syncthreads();
            }
            int run = s_scan[tid] - localcnt;
            for (int t = 0; t < CHUNK_; ++t) {
                if (mkbits & (1u << t)) {
                    int jj = j0 + t;
                    s_sup[jj] = 1;
                    if (run < NEIGH_) s_sel[jj] = 1;   // cumsum(mask) <= 16
                    ++run;
                }
            }
            if (tid == 0) { s_sup[i] = 1; s_sel[i] = 1; }  // ar == i term
            ++cnt;
        }
        ++i;
        __syncthreads();
    }

    // ---- init compaction fills ----
    for (int jj = tid; jj < M_; jj += NT_) s_unsupidx[jj] = M_ - 1;
    if (tid < TOTAL_) s_selidx[tid] = M_ - 1;
    __syncthreads();

    // ---- sel compaction ----
    {
        int localcnt = 0;
        for (int jj = j0; jj < j1; ++jj) localcnt += s_sel[jj];
        s_scan[tid] = localcnt;
        __syncthreads();
        for (int off = 1; off < NT_; off <<= 1) {
            int t = (tid >= off) ? s_scan[tid - off] : 0;
            __syncthreads();
            s_scan[tid] += t;
            __syncthreads();
        }
        if (tid == 0) s_nsel = s_scan[NT_ - 1];
        int run = s_scan[tid] - localcnt;
        for (int jj = j0; jj < j1; ++jj) {
            if (s_sel[jj]) { if (run < TOTAL_) s_selidx[run] = jj; ++run; }
        }
    }
    __syncthreads();

    // ---- unsup compaction ----
    {
        int localcnt = 0;
        for (int jj = j0; jj < j1; ++jj) localcnt += (s_sup[jj] == 0);
        s_scan[tid] = localcnt;
        __syncthreads();
        for (int off = 1; off < NT_; off <<= 1) {
            int t = (tid >= off) ? s_scan[tid - off] : 0;
            __syncthreads();
            s_scan[tid] += t;
            __syncthreads();
        }
        if (tid == 0) s_nunsup = s_scan[NT_ - 1];
        int run = s_scan[tid] - localcnt;
        for (int jj = j0; jj < j1; ++jj) {
            if (s_sup[jj] == 0) { s_unsupidx[run] = jj; ++run; }
        }
    }
    __syncthreads();

    // ---- final 101 indices + small outputs ----
    if (tid < KOUT_) {
        const int n_unsup = s_nunsup;
        const int n_sel   = s_nsel;
        int idx_sorted;
        if (tid < NEG_) {
            int t = n_unsup - 1 - tid;
            if (t < 0) t = 0;
            idx_sorted = s_unsupidx[t];
        } else {
            int p   = tid - NEG_;
            int pad = TOTAL_ - n_sel;
            idx_sorted = (p < pad) ? s_unsupidx[p] : s_selidx[p - pad];
        }
        int o = s_idx[idx_sorted];        // back to original proposal index
        int r = s_r[o], c = s_c[o];
        int gk = b * KOUT_ + tid;
        out_pse[2 * gk + 0] = (float)r;
        out_pse[2 * gk + 1] = (float)(c + 1);
        const float* og = offset_gt + ((size_t)b * N_ * N_ + r * N_ + c) * 2;
        out_off[2 * gk + 0] = og[0];
        out_off[2 * gk + 1] = og[1];
        out_score[gk] = tmap[(size_t)b * N_ * N_ + r * N_ + c];
    }
}

// ---------------------------------------------------------------------------
// Kernel 2: gather prop_feature rows (one block per output row, float4 copy).
// Recovers (r,c) from out_pse (exact int-valued floats) -> no d_ws needed.
// ---------------------------------------------------------------------------
__global__ __launch_bounds__(128) void gather_kernel(
    const float* __restrict__ map2d,        // [B,64,64,512]
    const float* __restrict__ out_pse,      // [B*K,2]
    float* __restrict__ out_feat)           // [B*K,512]
{
    int gk = blockIdx.x;
    int b  = gk / KOUT_;
    int r  = (int)out_pse[2 * gk + 0];
    int c  = (int)out_pse[2 * gk + 1] - 1;
    const float4* src = (const float4*)(map2d + ((size_t)b * N_ * N_ + r * N_ + c) * D_);
    float4*       dst = (float4*)(out_feat + (size_t)gk * D_);
    dst[threadIdx.x] = src[threadIdx.x];
}

extern "C" void kernel_launch(void* const* d_in, const int* in_sizes, int n_in,
                              void* d_out, int out_size, void* d_ws, size_t ws_size,
                              hipStream_t stream)
{
    const float* score_pred = (const float*)d_in[0];
    // d_in[1] = map2d_mask (deterministic triu mask, unused)
    const float* map2d      = (const float*)d_in[2];
    const float* offset_gt  = (const float*)d_in[3];
    const float* tmap       = (const float*)d_in[4];

    float* out       = (float*)d_out;
    float* out_feat  = out;                                   // [3232,512]
    float* out_pse   = out_feat + (size_t)B_ * KOUT_ * D_;    // [3232,2]
    float* out_off   = out_pse  + (size_t)B_ * KOUT_ * 2;     // [3232,2]
    float* out_score = out_off  + (size_t)B_ * KOUT_ * 2;     // [3232]

    select_kernel<<<B_, NT_, 0, stream>>>(score_pred, offset_gt, tmap,
                                          out_pse, out_off, out_score);
    gather_kernel<<<B_ * KOUT_, 128, 0, stream>>>(map2d, out_pse, out_feat);
}

// Round 2
// 346.933 us; speedup vs baseline: 1.4027x; 1.4027x over previous
//
#include <hip/hip_runtime.h>
#include <math.h>
#include <stdint.h>

#define N_      64
#define M_      2080          // N*(N+1)/2
#define SORTN   4096
#define B_      32
#define TOPK_   5
#define NEIGH_  16
#define NEG_    16
#define TOTAL_  85            // TOPK*(NEIGHBOR+1)
#define KOUT_   101           // NEGATIVE + TOTAL
#define D_      512
#define NT_     1024
#define NWAVE_  (NT_ / 64)    // 16
#define CHUNK_  3             // ceil(2080/1024)

// Exclusive block scan via wave shfl + 16-entry LDS combine. 3 barriers.
// After return, s_wsum[NWAVE_-1] holds the block total (stable until the
// next call's leading barrier).
__device__ __forceinline__ int block_scan_excl(int v, int tid, int* s_wsum)
{
    __syncthreads();                       // protect s_wsum reuse
    const int lane = tid & 63;
    const int wave = tid >> 6;
    int x = v;
#pragma unroll
    for (int off = 1; off < 64; off <<= 1) {
        int y = __shfl_up(x, off);
        if (lane >= off) x += y;
    }
    if (lane == 63) s_wsum[wave] = x;
    __syncthreads();
    if (wave == 0) {
        int w = (lane < NWAVE_) ? s_wsum[lane] : 0;
#pragma unroll
        for (int off = 1; off < NWAVE_; off <<= 1) {
            int y = __shfl_up(w, off);
            if (lane >= off) w += y;
        }
        if (lane < NWAVE_) s_wsum[lane] = w;   // inclusive wave totals
    }
    __syncthreads();
    int base = (wave > 0) ? s_wsum[wave - 1] : 0;
    return base + x - v;                   // exclusive prefix
}

// ---------------------------------------------------------------------------
// Kernel 1: per-batch proposal selection. One block (1024 thr) per batch.
// ---------------------------------------------------------------------------
__global__ __launch_bounds__(NT_) void select_kernel(
    const float* __restrict__ score_pred,   // [B,64,64]
    const float* __restrict__ offset_gt,    // [B,64,64,2]
    const float* __restrict__ tmap,         // [B,64,64]
    float* __restrict__ out_pse,            // [B*K,2]
    float* __restrict__ out_off,            // [B*K,2]
    float* __restrict__ out_score)          // [B*K]
{
    __shared__ uint64_t s_kv[SORTN];                 // 32 KB: key<<32 | idx
    __shared__ unsigned char s_r[M_], s_c[M_];
    __shared__ unsigned char sm_s[M_], sm_e[M_];     // sorted moments
    __shared__ unsigned char s_sup[M_], s_sel[M_];
    __shared__ int s_unsupidx[M_];
    __shared__ int s_selidx[TOTAL_];
    __shared__ int s_wsum[NWAVE_];

    const int b   = blockIdx.x;
    const int tid = threadIdx.x;

    // ---- m -> (r,c) triangle table ----
    if (tid < N_) {
        int r  = tid;
        int rs = r * N_ - (r * (r - 1)) / 2;
        for (int k = 0; k < N_ - r; ++k) {
            s_r[rs + k] = (unsigned char)r;
            s_c[rs + k] = (unsigned char)(r + k);
        }
    }
    __syncthreads();

    // ---- load scores, pack sortable uint64 keys ----
    // ascending uint64 sort == descending score, ties ascending original idx
    const float* sp = score_pred + (size_t)b * N_ * N_;
    for (int m = tid; m < SORTN; m += NT_) {
        uint64_t kv;
        if (m < M_) {
            int r = s_r[m], c = s_c[m];
            uint32_t fb  = __float_as_uint(sp[r * N_ + c]);
            uint32_t ord = (fb & 0x80000000u) ? ~fb : (fb | 0x80000000u); // ascending map
            uint32_t dk  = ~ord;                                          // descending
            kv = ((uint64_t)dk << 32) | (uint32_t)m;
        } else {
            kv = ~0ULL;                     // pad: sorts to the end
        }
        s_kv[m] = kv;
    }
    __syncthreads();

    // ---- bitonic sort (ascending uint64), 2 pairs per thread per pass ----
    for (int kk = 2; kk <= SORTN; kk <<= 1) {
        for (int j = kk >> 1; j > 0; j >>= 1) {
            const int jm = j - 1;
            // pair p0 = tid, p1 = tid + NT_ — unrolled for ILP
            int p0 = tid;
            int p1 = tid + NT_;
            int i0 = ((p0 & ~jm) << 1) | (p0 & jm);
            int i1 = ((p1 & ~jm) << 1) | (p1 & jm);
            uint64_t a0 = s_kv[i0], b0 = s_kv[i0 + j];
            uint64_t a1 = s_kv[i1], b1 = s_kv[i1 + j];
            bool up0 = ((i0 & kk) == 0);
            bool up1 = ((i1 & kk) == 0);
            bool sw0 = up0 ? (a0 > b0) : (a0 < b0);
            bool sw1 = up1 ? (a1 > b1) : (a1 < b1);
            if (sw0) { s_kv[i0] = b0; s_kv[i0 + j] = a0; }
            if (sw1) { s_kv[i1] = b1; s_kv[i1 + j] = a1; }
            __syncthreads();
        }
    }

    // ---- sorted moments + init ----
    for (int jj = tid; jj < M_; jj += NT_) {
        int o = (int)(uint32_t)s_kv[jj];
        sm_s[jj] = s_r[o];
        sm_e[jj] = (unsigned char)(s_c[o] + 1);
        s_sup[jj] = 0;
        s_sel[jj] = 0;
        s_unsupidx[jj] = M_ - 1;
    }
    if (tid < TOTAL_) s_selidx[tid] = M_ - 1;
    __syncthreads();

    // ---- NMS while-loop (block-uniform control flow) ----
    const int j0 = tid * CHUNK_;
    int i = 0, cnt = 0;
    while (cnt < TOPK_ && i < M_ - 1) {
        bool freei = (s_sup[i] == 0);
        if (freei) {
            const int si = sm_s[i], ei = sm_e[i];
            unsigned int mkbits = 0;
            int localcnt = 0;
#pragma unroll
            for (int t = 0; t < CHUNK_; ++t) {
                int jj = j0 + t;
                if (jj < M_ && jj > i) {
                    int s = sm_s[jj], e = sm_e[jj];
                    int inter = (e < ei ? e : ei) - (s > si ? s : si);
                    int uni   = (e > ei ? e : ei) - (s < si ? s : si);
                    if (inter > 0 && 2 * inter > uni) {   // iou > 0.5, exact
                        mkbits |= (1u << t);
                        ++localcnt;
                    }
                }
            }
            int run = block_scan_excl(localcnt, tid, s_wsum);
#pragma unroll
            for (int t = 0; t < CHUNK_; ++t) {
                if (mkbits & (1u << t)) {
                    int jj = j0 + t;
                    s_sup[jj] = 1;
                    if (run < NEIGH_) s_sel[jj] = 1;     // cumsum(mask) <= 16
                    ++run;
                }
            }
            if (tid == 0) { s_sup[i] = 1; s_sel[i] = 1; }
            ++cnt;
        }
        ++i;
        __syncthreads();
    }

    // ---- sel compaction ----
    int n_sel, n_unsup;
    {
        int localcnt = 0;
#pragma unroll
        for (int t = 0; t < CHUNK_; ++t) {
            int jj = j0 + t;
            if (jj < M_) localcnt += s_sel[jj];
        }
        int run = block_scan_excl(localcnt, tid, s_wsum);
        n_sel = s_wsum[NWAVE_ - 1];
#pragma unroll
        for (int t = 0; t < CHUNK_; ++t) {
            int jj = j0 + t;
            if (jj < M_ && s_sel[jj]) {
                if (run < TOTAL_) s_selidx[run] = jj;
                ++run;
            }
        }
    }
    // ---- unsup compaction ----
    {
        int localcnt = 0;
#pragma unroll
        for (int t = 0; t < CHUNK_; ++t) {
            int jj = j0 + t;
            if (jj < M_) localcnt += (s_sup[jj] == 0);
        }
        int run = block_scan_excl(localcnt, tid, s_wsum);
        n_unsup = s_wsum[NWAVE_ - 1];
#pragma unroll
        for (int t = 0; t < CHUNK_; ++t) {
            int jj = j0 + t;
            if (jj < M_ && s_sup[jj] == 0) {
                s_unsupidx[run] = jj;
                ++run;
            }
        }
    }
    __syncthreads();

    // ---- final 101 indices + small outputs ----
    if (tid < KOUT_) {
        int idx_sorted;
        if (tid < NEG_) {
            int t = n_unsup - 1 - tid;
            if (t < 0) t = 0;
            idx_sorted = s_unsupidx[t];
        } else {
            int p   = tid - NEG_;
            int pad = TOTAL_ - n_sel;
            idx_sorted = (p < pad) ? s_unsupidx[p] : s_selidx[p - pad];
        }
        int o = (int)(uint32_t)s_kv[idx_sorted];   // original proposal index
        int r = s_r[o], c = s_c[o];
        int gk = b * KOUT_ + tid;
        out_pse[2 * gk + 0] = (float)r;
        out_pse[2 * gk + 1] = (float)(c + 1);
        const float* og = offset_gt + ((size_t)b * N_ * N_ + r * N_ + c) * 2;
        out_off[2 * gk + 0] = og[0];
        out_off[2 * gk + 1] = og[1];
        out_score[gk] = tmap[(size_t)b * N_ * N_ + r * N_ + c];
    }
}

// ---------------------------------------------------------------------------
// Kernel 2: gather prop_feature rows (one block per output row, float4 copy).
// ---------------------------------------------------------------------------
__global__ __launch_bounds__(128) void gather_kernel(
    const float* __restrict__ map2d,        // [B,64,64,512]
    const float* __restrict__ out_pse,      // [B*K,2]
    float* __restrict__ out_feat)           // [B*K,512]
{
    int gk = blockIdx.x;
    int b  = gk / KOUT_;
    int r  = (int)out_pse[2 * gk + 0];
    int c  = (int)out_pse[2 * gk + 1] - 1;
    const float4* src = (const float4*)(map2d + ((size_t)b * N_ * N_ + r * N_ + c) * D_);
    float4*       dst = (float4*)(out_feat + (size_t)gk * D_);
    dst[threadIdx.x] = src[threadIdx.x];
}

extern "C" void kernel_launch(void* const* d_in, const int* in_sizes, int n_in,
                              void* d_out, int out_size, void* d_ws, size_t ws_size,
                              hipStream_t stream)
{
    const float* score_pred = (const float*)d_in[0];
    // d_in[1] = map2d_mask (deterministic triu mask, unused)
    const float* map2d      = (const float*)d_in[2];
    const float* offset_gt  = (const float*)d_in[3];
    const float* tmap       = (const float*)d_in[4];

    float* out       = (float*)d_out;
    float* out_feat  = out;                                   // [3232,512]
    float* out_pse   = out_feat + (size_t)B_ * KOUT_ * D_;    // [3232,2]
    float* out_off   = out_pse  + (size_t)B_ * KOUT_ * 2;     // [3232,2]
    float* out_score = out_off  + (size_t)B_ * KOUT_ * 2;     // [3232]

    select_kernel<<<B_, NT_, 0, stream>>>(score_pred, offset_gt, tmap,
                                          out_pse, out_off, out_score);
    gather_kernel<<<B_ * KOUT_, 128, 0, stream>>>(map2d, out_pse, out_feat);
}